// Round 6
// baseline (823.180 us; speedup 1.0000x reference)
//
#include <hip/hip_runtime.h>

typedef unsigned short u16;
typedef unsigned int u32;
typedef __attribute__((ext_vector_type(8))) __bf16 bf16x8;
typedef __attribute__((ext_vector_type(4))) float f32x4;

#define B_ 32
#define T_ 128
#define V_ 32000
#define H_ 512
#define L_ 3
#define LW 64  // workgroups per layer in the persistent LSTM kernel

__device__ __forceinline__ u16 f2bf(float x) {
  union { float f; u32 u; } v; v.f = x;
  u32 r = v.u + 0x7fffu + ((v.u >> 16) & 1u);  // RNE; finite in -> finite out
  return (u16)(r >> 16);
}
__device__ __forceinline__ float b2f(u16 h) {
  union { u32 u; float f; } v; v.u = ((u32)h) << 16; return v.f;
}
__device__ __forceinline__ float sigf(float x) { return 1.f / (1.f + __expf(-x)); }
__device__ __forceinline__ float tanhf_(float x) { return 2.f / (1.f + __expf(-2.f * x)) - 1.f; }

__device__ __forceinline__ void gload16(const void* g, void* l) {
  __builtin_amdgcn_global_load_lds((const __attribute__((address_space(1))) u32*)g,
                                   (__attribute__((address_space(3))) u32*)l, 16, 0, 0);
}

union F4B8 { f32x4 f; bf16x8 b; uint4 u; };

// L2-bypass (LLC-coherent) loads; caller must s_waitcnt vmcnt before use.
__device__ __forceinline__ void load16_sc1(const void* p, F4B8* dst) {
  asm volatile("global_load_dwordx4 %0, %1, off sc1" : "=v"(dst->f) : "v"(p));
}
__device__ __forceinline__ u32 load_dword_sc1_(const void* p) {
  u32 r;
  asm volatile("global_load_dword %0, %1, off sc1" : "=v"(r) : "v"(p));
  return r;
}
__device__ __forceinline__ void store_short_sc1(void* p, u32 v) {
  asm volatile("global_store_short %0, %1, off sc1" :: "v"(p), "v"(v));
}

// Sentinel check on LOADED registers: valid h/x (|v|<=1) has bit14==0 in every
// u16; the 0xFFFF prefill has bit14==1. Returns true if ANY lane saw a sentinel.
__device__ __forceinline__ bool frags_dirty(const F4B8* r) {
  u32 acc = 0;
#pragma unroll
  for (int i = 0; i < 16; ++i) acc |= r[i].u.x | r[i].u.y | r[i].u.z | r[i].u.w;
  return __ballot((acc & 0x40004000u) != 0u) != 0ull;
}

// ---------------- embedding lookup -> X[t][b][e] bf16 ----------------
__global__ __launch_bounds__(64) void k_embed(const int* __restrict__ idx,
                                              const float* __restrict__ emb,
                                              u16* __restrict__ X) {
  int bt = blockIdx.x;             // b*T + t
  int b = bt >> 7, t = bt & 127;
  int v = idx[bt];
  const float* src = emb + (size_t)v * H_;
  u16* dst = X + ((size_t)t * B_ + b) * H_;
  int l8 = threadIdx.x << 3;
  float4 f0 = *(const float4*)(src + l8);
  float4 f1 = *(const float4*)(src + l8 + 4);
  uint4 o;
  o.x = (u32)f2bf(f0.x) | ((u32)f2bf(f0.y) << 16);
  o.y = (u32)f2bf(f0.z) | ((u32)f2bf(f0.w) << 16);
  o.z = (u32)f2bf(f1.x) | ((u32)f2bf(f1.y) << 16);
  o.w = (u32)f2bf(f1.z) | ((u32)f2bf(f1.w) << 16);
  *(uint4*)(dst + l8) = o;
}

// ---------------- Wh [512][32000] f32 -> WhT [32000][512] bf16 ----------------
__global__ __launch_bounds__(256) void k_transpose(const float* __restrict__ Wh,
                                                   u16* __restrict__ WhT) {
  __shared__ u16 tile[64][66];
  int nb = blockIdx.x % 500, kb = blockIdx.x / 500;
  int n0 = nb << 6, k0 = kb << 6;
  int tid = threadIdx.x;
#pragma unroll
  for (int it = 0; it < 16; ++it) {
    int k = (it << 2) + (tid >> 6);
    int n = tid & 63;
    tile[k][n] = f2bf(Wh[(size_t)(k0 + k) * V_ + n0 + n]);
  }
  __syncthreads();
#pragma unroll
  for (int it = 0; it < 16; ++it) {
    int n = (it << 2) + (tid >> 6);
    int k = tid & 63;
    WhT[(size_t)(n0 + n) * H_ + k0 + k] = tile[k][n];
  }
}

// ---------------- persistent LSTM ----------------
// 192 wgs = 3 layers x 64 col-groups; wg owns h-cols [8g,8g+8) of its layer.
// Sync is DATA-EMBEDDED (bf16 sentinel 0xFFFF, bit14=1). Detect is decoupled
// from fetch: lane i spins on a 4-byte canary of producer i's slab (256B/wave
// per poll), then ONE full 16xdwordx4 load + authoritative register verify.
__global__ __launch_bounds__(128, 1) void k_lstm(const float* __restrict__ Wg,
                                                 const float* __restrict__ bias,
                                                 const u16* __restrict__ X,
                                                 u16* __restrict__ Hbuf) {
  __shared__ u16 bfrag[32][2][64][8];
  const int l = blockIdx.x / LW, g = blockIdx.x % LW;
  const int tid = threadIdx.x, wave = tid >> 6, lane = tid & 63;

  // --- one-time: W slice -> fragment-ordered LDS (bf16)
  const float* Wl = Wg + (size_t)l * 1024 * 2048;
  for (int f = tid; f < 4096; f += 128) {
    int kb = f >> 7, nt = (f >> 6) & 1, ln = f & 63;
    int n = (nt << 4) + (ln & 15);
    int col = ((n >> 3) << 9) + (g << 3) + (n & 7);  // 512*q + 8g + (n%8)
    int k0 = (kb << 5) + ((ln >> 4) << 3);
#pragma unroll
    for (int j = 0; j < 8; ++j)
      bfrag[kb][nt][ln][j] = f2bf(Wl[(size_t)(k0 + j) * 2048 + col]);
  }
  __syncthreads();
  bf16x8 wfh[16][2], wfx[16][2];
#pragma unroll
  for (int kb = 0; kb < 16; ++kb) {
    wfh[kb][0] = *(const bf16x8*)&bfrag[kb][0][lane][0];
    wfh[kb][1] = *(const bf16x8*)&bfrag[kb][1][lane][0];
    wfx[kb][0] = *(const bf16x8*)&bfrag[16 + kb][0][lane][0];
    wfx[kb][1] = *(const bf16x8*)&bfrag[16 + kb][1][lane][0];
  }

  const int jj = lane & 7, cg = (g << 3) + jj;
  const float bF = bias[l * 2048 + cg];
  const float bI = bias[l * 2048 + 512 + cg];
  const float bG = bias[l * 2048 + 1024 + cg];
  const float bO = bias[l * 2048 + 1536 + cg];
  float cst[4] = {0.f, 0.f, 0.f, 0.f};

  const size_t slice = (size_t)B_ * H_;
  u16* Hl = Hbuf + (size_t)l * (T_ + 1) * slice;
  const u16* inb = (l == 0) ? X : (Hbuf + (size_t)(l - 1) * (T_ + 1) * slice + slice);

  const int mrow = (wave << 4) + (lane & 15);  // batch row of A fragment
  const int koff = ((lane >> 4) << 3);

  // canary: lane i polls u32 at (own row, cols 8i..8i+1) = producer wg i's slab
  auto wait_canary = [&](const u16* sbase) {
    const u16* cp = sbase + (size_t)mrow * H_ + ((size_t)lane << 3);
    for (;;) {
      u32 v = load_dword_sc1_(cp);
      asm volatile("s_waitcnt vmcnt(0)" ::: "memory");
      if (__ballot((v & 0x40004000u) != 0u) == 0ull) return;
    }
  };

  f32x4 z = {0.f, 0.f, 0.f, 0.f};
  f32x4 pxA0 = z, pxA1 = z, pxB0 = z, pxB1 = z;  // x-part accs, carried over

  // x-part of step t into px accs; for l>0 canary-wait then verified load
  auto do_x = [&](int t) {
    const u16* sbase = inb + (size_t)t * slice;
    const u16* xin = sbase + (size_t)mrow * H_ + koff;
    F4B8 ax[16];
    if (l == 0) {
#pragma unroll
      for (int kb = 0; kb < 16; ++kb) ax[kb].b = *(const bf16x8*)(xin + (kb << 5));
    } else {
      wait_canary(sbase);
      for (;;) {
#pragma unroll
        for (int kb = 0; kb < 16; ++kb) load16_sc1(xin + (kb << 5), &ax[kb]);
        asm volatile("s_waitcnt vmcnt(0)" ::: "memory");
        __builtin_amdgcn_sched_barrier(0);
        if (!frags_dirty(ax)) break;
      }
    }
    pxA0 = z; pxA1 = z; pxB0 = z; pxB1 = z;
#pragma unroll
    for (int kb = 0; kb < 16; kb += 2) {
      pxA0 = __builtin_amdgcn_mfma_f32_16x16x32_bf16(ax[kb].b, wfx[kb][0], pxA0, 0, 0, 0);
      pxA1 = __builtin_amdgcn_mfma_f32_16x16x32_bf16(ax[kb].b, wfx[kb][1], pxA1, 0, 0, 0);
      pxB0 = __builtin_amdgcn_mfma_f32_16x16x32_bf16(ax[kb + 1].b, wfx[kb + 1][0], pxB0, 0, 0, 0);
      pxB1 = __builtin_amdgcn_mfma_f32_16x16x32_bf16(ax[kb + 1].b, wfx[kb + 1][1], pxB1, 0, 0, 0);
    }
  };

  do_x(0);

  for (int t = 0; t < T_; ++t) {
    // ---- h-part: own layer's h[t]; canary-wait, one verified load, MFMA once ----
    f32x4 hA0 = z, hA1 = z, hB0 = z, hB1 = z;
    f32x4 hC0 = z, hC1 = z, hD0 = z, hD1 = z;
    if (t > 0) {
      const u16* sbase = Hl + (size_t)t * slice;
      const u16* hin = sbase + (size_t)mrow * H_ + koff;
      F4B8 ah[16];
      wait_canary(sbase);
      for (;;) {
#pragma unroll
        for (int kb = 0; kb < 16; ++kb) load16_sc1(hin + (kb << 5), &ah[kb]);
        asm volatile("s_waitcnt vmcnt(0)" ::: "memory");
        __builtin_amdgcn_sched_barrier(0);
        if (!frags_dirty(ah)) break;
      }
#pragma unroll
      for (int kb = 0; kb < 16; kb += 4) {
        hA0 = __builtin_amdgcn_mfma_f32_16x16x32_bf16(ah[kb].b, wfh[kb][0], hA0, 0, 0, 0);
        hA1 = __builtin_amdgcn_mfma_f32_16x16x32_bf16(ah[kb].b, wfh[kb][1], hA1, 0, 0, 0);
        hB0 = __builtin_amdgcn_mfma_f32_16x16x32_bf16(ah[kb + 1].b, wfh[kb + 1][0], hB0, 0, 0, 0);
        hB1 = __builtin_amdgcn_mfma_f32_16x16x32_bf16(ah[kb + 1].b, wfh[kb + 1][1], hB1, 0, 0, 0);
        hC0 = __builtin_amdgcn_mfma_f32_16x16x32_bf16(ah[kb + 2].b, wfh[kb + 2][0], hC0, 0, 0, 0);
        hC1 = __builtin_amdgcn_mfma_f32_16x16x32_bf16(ah[kb + 2].b, wfh[kb + 2][1], hC1, 0, 0, 0);
        hD0 = __builtin_amdgcn_mfma_f32_16x16x32_bf16(ah[kb + 3].b, wfh[kb + 3][0], hD0, 0, 0, 0);
        hD1 = __builtin_amdgcn_mfma_f32_16x16x32_bf16(ah[kb + 3].b, wfh[kb + 3][1], hD1, 0, 0, 0);
      }
    }
    // ---- cell math via shfl (no LDS), redundant in half-lanes, store h ----
    {
      f32x4 s0, s1, q0, q1;
#pragma unroll
      for (int r = 0; r < 4; ++r) {
        s0[r] = pxA0[r] + pxB0[r] + ((hA0[r] + hB0[r]) + (hC0[r] + hD0[r]));
        s1[r] = pxA1[r] + pxB1[r] + ((hA1[r] + hB1[r]) + (hC1[r] + hD1[r]));
      }
#pragma unroll
      for (int r = 0; r < 4; ++r) { q0[r] = __shfl_xor(s0[r], 8); q1[r] = __shfl_xor(s1[r], 8); }
      const bool lo = (lane & 8) == 0;
      float hv[4];
#pragma unroll
      for (int r = 0; r < 4; ++r) {
        float fr = lo ? s0[r] : q0[r];
        float ir = lo ? q0[r] : s0[r];
        float gr = lo ? s1[r] : q1[r];
        float orr = lo ? q1[r] : s1[r];
        float cc = sigf(fr + bF) * cst[r] + sigf(ir + bI) * tanhf_(gr + bG);
        cst[r] = cc;
        hv[r] = sigf(orr + bO) * tanhf_(cc);
      }
      if (lo) {
        int rbase = (wave << 4) + ((lane >> 4) << 2);
        u16* hp = Hl + (size_t)(t + 1) * slice + cg;
#pragma unroll
        for (int r = 0; r < 4; ++r)
          store_short_sc1(hp + (size_t)(rbase + r) * H_, (u32)f2bf(hv[r]));
      }
    }
    // ---- x-part of step t+1 (off the recurrence chain) ----
    if (t + 1 < T_) do_x(t + 1);
  }
}

// ---------------- LayerNorm: Hbuf[2][t+1][b][:] -> Aln[b*T+t][:] bf16 ----------------
__global__ __launch_bounds__(64) void k_ln(const u16* __restrict__ H2,
                                           const float* __restrict__ gamma,
                                           const float* __restrict__ beta,
                                           u16* __restrict__ Aln) {
  int bt = blockIdx.x;
  int b = bt >> 7, t = bt & 127;
  const u16* src = H2 + ((size_t)(t + 1) * B_ + b) * H_;
  int l8 = threadIdx.x << 3;
  uint4 r = *(const uint4*)(src + l8);
  float v[8];
  v[0] = b2f(r.x & 0xffff); v[1] = b2f(r.x >> 16);
  v[2] = b2f(r.y & 0xffff); v[3] = b2f(r.y >> 16);
  v[4] = b2f(r.z & 0xffff); v[5] = b2f(r.z >> 16);
  v[6] = b2f(r.w & 0xffff); v[7] = b2f(r.w >> 16);
  float s = 0.f, sq = 0.f;
#pragma unroll
  for (int i = 0; i < 8; ++i) { s += v[i]; sq += v[i] * v[i]; }
#pragma unroll
  for (int off = 32; off > 0; off >>= 1) {
    s += __shfl_xor(s, off);
    sq += __shfl_xor(sq, off);
  }
  float mu = s * (1.f / 512.f);
  float inv = rsqrtf(sq * (1.f / 512.f) - mu * mu + 1e-5f);
  float4 g0 = *(const float4*)(gamma + l8), g1 = *(const float4*)(gamma + l8 + 4);
  float4 be0 = *(const float4*)(beta + l8), be1 = *(const float4*)(beta + l8 + 4);
  float gg[8] = {g0.x, g0.y, g0.z, g0.w, g1.x, g1.y, g1.z, g1.w};
  float bb[8] = {be0.x, be0.y, be0.z, be0.w, be1.x, be1.y, be1.z, be1.w};
  u16 o16[8];
#pragma unroll
  for (int i = 0; i < 8; ++i) o16[i] = f2bf((v[i] - mu) * inv * gg[i] + bb[i]);
  uint4 o;
  o.x = (u32)o16[0] | ((u32)o16[1] << 16);
  o.y = (u32)o16[2] | ((u32)o16[3] << 16);
  o.z = (u32)o16[4] | ((u32)o16[5] << 16);
  o.w = (u32)o16[6] | ((u32)o16[7] << 16);
  *(uint4*)(Aln + (size_t)bt * H_ + l8) = o;
}

// ---------------- projection: C[4096][32000] = Aln @ WhT^T + bh ----------------
__global__ __launch_bounds__(256) void k_gemm(const u16* __restrict__ A,
                                              const u16* __restrict__ Bt,
                                              const float* __restrict__ bh,
                                              float* __restrict__ C) {
  __shared__ u16 As[128 * 64], Bs[128 * 64];
  const int bid = blockIdx.x;
  const int mb = bid / 250, nb = bid % 250;
  const size_t arow0 = (size_t)mb << 7;
  const size_t bcol0 = (size_t)nb << 7;
  const int tid = threadIdx.x, wave = tid >> 6, lane = tid & 63;
  const int wm = wave & 1, wn = wave >> 1;
  f32x4 acc[4][4];
  f32x4 z = {0.f, 0.f, 0.f, 0.f};
#pragma unroll
  for (int i = 0; i < 4; ++i)
#pragma unroll
    for (int jj = 0; jj < 4; ++jj) acc[i][jj] = z;

  for (int kt = 0; kt < 8; ++kt) {
#pragma unroll
    for (int it = 0; it < 4; ++it) {
      int rb = (it << 5) + (wave << 3);
      int r = rb + (lane >> 3);
      int kc = ((lane & 7) << 3);
      gload16(A + (arow0 + r) * H_ + (kt << 6) + kc, &As[rb << 6]);
      gload16(Bt + (bcol0 + r) * H_ + (kt << 6) + kc, &Bs[rb << 6]);
    }
    __syncthreads();
#pragma unroll
    for (int kb = 0; kb < 2; ++kb) {
      bf16x8 af[4], bf[4];
#pragma unroll
      for (int mi = 0; mi < 4; ++mi)
        af[mi] = *(const bf16x8*)&As[(((wm << 6) + (mi << 4) + (lane & 15)) << 6) + (kb << 5) + ((lane >> 4) << 3)];
#pragma unroll
      for (int ni = 0; ni < 4; ++ni)
        bf[ni] = *(const bf16x8*)&Bs[(((wn << 6) + (ni << 4) + (lane & 15)) << 6) + (kb << 5) + ((lane >> 4) << 3)];
#pragma unroll
      for (int mi = 0; mi < 4; ++mi)
#pragma unroll
        for (int ni = 0; ni < 4; ++ni)
          acc[mi][ni] = __builtin_amdgcn_mfma_f32_16x16x32_bf16(af[mi], bf[ni], acc[mi][ni], 0, 0, 0);
    }
    __syncthreads();
  }
  const int rb4 = ((lane >> 4) << 2), n0 = lane & 15;
#pragma unroll
  for (int ni = 0; ni < 4; ++ni) {
    size_t col = bcol0 + (wn << 6) + (ni << 4) + n0;
    float bv = bh[col];
#pragma unroll
    for (int mi = 0; mi < 4; ++mi) {
      size_t row = arow0 + (wm << 6) + (mi << 4) + rb4;
#pragma unroll
      for (int r = 0; r < 4; ++r)
        C[(row + r) * V_ + col] = acc[mi][ni][r] + bv;
    }
  }
}

extern "C" void kernel_launch(void* const* d_in, const int* in_sizes, int n_in,
                              void* d_out, int out_size, void* d_ws, size_t ws_size,
                              hipStream_t stream) {
  const int* idx = (const int*)d_in[0];
  const float* emb = (const float*)d_in[1];
  const float* Wg = (const float*)d_in[2];
  const float* bias = (const float*)d_in[3];
  const float* gamma = (const float*)d_in[4];
  const float* beta = (const float*)d_in[5];
  const float* Wh = (const float*)d_in[6];
  const float* bh = (const float*)d_in[7];
  float* out = (float*)d_out;

  char* ws = (char*)d_ws;
  const size_t szX = (size_t)T_ * B_ * H_ * 2;             // x embedding, bf16
  const size_t szH = (size_t)L_ * (T_ + 1) * B_ * H_ * 2;  // h history, bf16
  const size_t szA = (size_t)B_ * T_ * H_ * 2;             // LN output, bf16
  const size_t szW = (size_t)V_ * H_ * 2;                  // WhT, bf16
  u16* X = (u16*)ws;
  u16* Hbuf = (u16*)(ws + szX);
  u16* Aln = (u16*)(ws + szX + szH);
  u16* WhT = (u16*)(ws + szX + szH + szA);
  if (ws_size < szX + szH + szA + szW) return;

  const size_t slice = (size_t)B_ * H_;
  // Sentinel fill (0xFF bytes -> bf16 0xFFFF, bit14=1) for all t>=1 slices;
  // slice 0 of each layer = h(-1) = 0.
  hipMemsetAsync(Hbuf, 0xFF, szH, stream);
  for (int l = 0; l < L_; ++l)
    hipMemsetAsync(Hbuf + (size_t)l * (T_ + 1) * slice, 0, slice * 2, stream);
  k_embed<<<B_ * T_, 64, 0, stream>>>(idx, emb, X);
  k_transpose<<<500 * 8, 256, 0, stream>>>(Wh, WhT);
  k_lstm<<<L_ * LW, 128, 0, stream>>>(Wg, bias, X, Hbuf);
  k_ln<<<B_ * T_, 64, 0, stream>>>(Hbuf + (size_t)2 * (T_ + 1) * B_ * H_, gamma, beta, Aln);
  k_gemm<<<32 * 250, 256, 0, stream>>>(Aln, WhT, bh, out);
}

// Round 7
// 732.135 us; speedup vs baseline: 1.1244x; 1.1244x over previous
//
#include <hip/hip_runtime.h>

typedef unsigned short u16;
typedef unsigned int u32;
typedef __attribute__((ext_vector_type(8))) __bf16 bf16x8;
typedef __attribute__((ext_vector_type(4))) float f32x4;

#define B_ 32
#define T_ 128
#define V_ 32000
#define H_ 512
#define L_ 3
#define LW 64  // workgroups per layer in the persistent LSTM kernel

__device__ __forceinline__ u16 f2bf(float x) {
  union { float f; u32 u; } v; v.f = x;
  u32 r = v.u + 0x7fffu + ((v.u >> 16) & 1u);  // RNE; finite in -> finite out
  return (u16)(r >> 16);
}
__device__ __forceinline__ float b2f(u16 h) {
  union { u32 u; float f; } v; v.u = ((u32)h) << 16; return v.f;
}
__device__ __forceinline__ float sigf(float x) { return 1.f / (1.f + __expf(-x)); }
__device__ __forceinline__ float tanhf_(float x) { return 2.f / (1.f + __expf(-2.f * x)) - 1.f; }

__device__ __forceinline__ void gload16(const void* g, void* l) {
  __builtin_amdgcn_global_load_lds((const __attribute__((address_space(1))) u32*)g,
                                   (__attribute__((address_space(3))) u32*)l, 16, 0, 0);
}

union F4B8 { f32x4 f; bf16x8 b; uint4 u; };

// L2-bypass (LLC-coherent) loads; caller must s_waitcnt vmcnt before use.
__device__ __forceinline__ void load16_sc1(const void* p, F4B8* dst) {
  asm volatile("global_load_dwordx4 %0, %1, off sc1" : "=v"(dst->f) : "v"(p));
}
__device__ __forceinline__ void store_short_sc1(void* p, u32 v) {
  asm volatile("global_store_short %0, %1, off sc1" :: "v"(p), "v"(v));
}

// Sentinel check on LOADED registers: valid h/x (|v|<=1) has bit14==0 in every
// u16; the 0xFFFF prefill has bit14==1. Returns true if ANY lane saw a sentinel.
__device__ __forceinline__ bool frags_dirty(const F4B8* r) {
  u32 acc = 0;
#pragma unroll
  for (int i = 0; i < 16; ++i) acc |= r[i].u.x | r[i].u.y | r[i].u.z | r[i].u.w;
  return __ballot((acc & 0x40004000u) != 0u) != 0ull;
}

// ---------------- embedding lookup -> X[t][b][e] bf16 ----------------
__global__ __launch_bounds__(64) void k_embed(const int* __restrict__ idx,
                                              const float* __restrict__ emb,
                                              u16* __restrict__ X) {
  int bt = blockIdx.x;             // b*T + t
  int b = bt >> 7, t = bt & 127;
  int v = idx[bt];
  const float* src = emb + (size_t)v * H_;
  u16* dst = X + ((size_t)t * B_ + b) * H_;
  int l8 = threadIdx.x << 3;
  float4 f0 = *(const float4*)(src + l8);
  float4 f1 = *(const float4*)(src + l8 + 4);
  uint4 o;
  o.x = (u32)f2bf(f0.x) | ((u32)f2bf(f0.y) << 16);
  o.y = (u32)f2bf(f0.z) | ((u32)f2bf(f0.w) << 16);
  o.z = (u32)f2bf(f1.x) | ((u32)f2bf(f1.y) << 16);
  o.w = (u32)f2bf(f1.z) | ((u32)f2bf(f1.w) << 16);
  *(uint4*)(dst + l8) = o;
}

// ---------------- Wh [512][32000] f32 -> WhT [32000][512] bf16 ----------------
__global__ __launch_bounds__(256) void k_transpose(const float* __restrict__ Wh,
                                                   u16* __restrict__ WhT) {
  __shared__ u16 tile[64][66];
  int nb = blockIdx.x % 500, kb = blockIdx.x / 500;
  int n0 = nb << 6, k0 = kb << 6;
  int tid = threadIdx.x;
#pragma unroll
  for (int it = 0; it < 16; ++it) {
    int k = (it << 2) + (tid >> 6);
    int n = tid & 63;
    tile[k][n] = f2bf(Wh[(size_t)(k0 + k) * V_ + n0 + n]);
  }
  __syncthreads();
#pragma unroll
  for (int it = 0; it < 16; ++it) {
    int n = (it << 2) + (tid >> 6);
    int k = tid & 63;
    WhT[(size_t)(n0 + n) * H_ + k0 + k] = tile[k][n];
  }
}

// ---------------- persistent LSTM (R5 form: best measured 497 us) ----------------
__global__ __launch_bounds__(128, 1) void k_lstm(const float* __restrict__ Wg,
                                                 const float* __restrict__ bias,
                                                 const u16* __restrict__ X,
                                                 u16* __restrict__ Hbuf) {
  __shared__ u16 bfrag[32][2][64][8];
  const int l = blockIdx.x / LW, g = blockIdx.x % LW;
  const int tid = threadIdx.x, wave = tid >> 6, lane = tid & 63;

  const float* Wl = Wg + (size_t)l * 1024 * 2048;
  for (int f = tid; f < 4096; f += 128) {
    int kb = f >> 7, nt = (f >> 6) & 1, ln = f & 63;
    int n = (nt << 4) + (ln & 15);
    int col = ((n >> 3) << 9) + (g << 3) + (n & 7);  // 512*q + 8g + (n%8)
    int k0 = (kb << 5) + ((ln >> 4) << 3);
#pragma unroll
    for (int j = 0; j < 8; ++j)
      bfrag[kb][nt][ln][j] = f2bf(Wl[(size_t)(k0 + j) * 2048 + col]);
  }
  __syncthreads();
  bf16x8 wfh[16][2], wfx[16][2];
#pragma unroll
  for (int kb = 0; kb < 16; ++kb) {
    wfh[kb][0] = *(const bf16x8*)&bfrag[kb][0][lane][0];
    wfh[kb][1] = *(const bf16x8*)&bfrag[kb][1][lane][0];
    wfx[kb][0] = *(const bf16x8*)&bfrag[16 + kb][0][lane][0];
    wfx[kb][1] = *(const bf16x8*)&bfrag[16 + kb][1][lane][0];
  }

  const int jj = lane & 7, cg = (g << 3) + jj;
  const float bF = bias[l * 2048 + cg];
  const float bI = bias[l * 2048 + 512 + cg];
  const float bG = bias[l * 2048 + 1024 + cg];
  const float bO = bias[l * 2048 + 1536 + cg];
  float cst[4] = {0.f, 0.f, 0.f, 0.f};

  const size_t slice = (size_t)B_ * H_;
  u16* Hl = Hbuf + (size_t)l * (T_ + 1) * slice;
  const u16* inb = (l == 0) ? X : (Hbuf + (size_t)(l - 1) * (T_ + 1) * slice + slice);

  const int mrow = (wave << 4) + (lane & 15);  // batch row of A fragment
  const int koff = ((lane >> 4) << 3);

  f32x4 z = {0.f, 0.f, 0.f, 0.f};
  f32x4 pxA0 = z, pxA1 = z, pxB0 = z, pxB1 = z;  // x-part accs, carried over

  auto do_x = [&](int t) {
    const u16* xin = inb + (size_t)t * slice + (size_t)mrow * H_ + koff;
    F4B8 ax[16];
    if (l == 0) {
#pragma unroll
      for (int kb = 0; kb < 16; ++kb) ax[kb].b = *(const bf16x8*)(xin + (kb << 5));
    } else {
      for (;;) {
#pragma unroll
        for (int kb = 0; kb < 16; ++kb) load16_sc1(xin + (kb << 5), &ax[kb]);
        asm volatile("s_waitcnt vmcnt(0)" ::: "memory");
        __builtin_amdgcn_sched_barrier(0);
        if (!frags_dirty(ax)) break;
      }
    }
    pxA0 = z; pxA1 = z; pxB0 = z; pxB1 = z;
#pragma unroll
    for (int kb = 0; kb < 16; kb += 2) {
      pxA0 = __builtin_amdgcn_mfma_f32_16x16x32_bf16(ax[kb].b, wfx[kb][0], pxA0, 0, 0, 0);
      pxA1 = __builtin_amdgcn_mfma_f32_16x16x32_bf16(ax[kb].b, wfx[kb][1], pxA1, 0, 0, 0);
      pxB0 = __builtin_amdgcn_mfma_f32_16x16x32_bf16(ax[kb + 1].b, wfx[kb + 1][0], pxB0, 0, 0, 0);
      pxB1 = __builtin_amdgcn_mfma_f32_16x16x32_bf16(ax[kb + 1].b, wfx[kb + 1][1], pxB1, 0, 0, 0);
    }
  };

  do_x(0);

  for (int t = 0; t < T_; ++t) {
    f32x4 hA0 = z, hA1 = z, hB0 = z, hB1 = z;
    f32x4 hC0 = z, hC1 = z, hD0 = z, hD1 = z;
    if (t > 0) {
      const u16* hin = Hl + (size_t)t * slice + (size_t)mrow * H_ + koff;
      F4B8 ah[16];
      for (;;) {
#pragma unroll
        for (int kb = 0; kb < 16; ++kb) load16_sc1(hin + (kb << 5), &ah[kb]);
        asm volatile("s_waitcnt vmcnt(0)" ::: "memory");
        __builtin_amdgcn_sched_barrier(0);
        if (!frags_dirty(ah)) break;
      }
#pragma unroll
      for (int kb = 0; kb < 16; kb += 4) {
        hA0 = __builtin_amdgcn_mfma_f32_16x16x32_bf16(ah[kb].b, wfh[kb][0], hA0, 0, 0, 0);
        hA1 = __builtin_amdgcn_mfma_f32_16x16x32_bf16(ah[kb].b, wfh[kb][1], hA1, 0, 0, 0);
        hB0 = __builtin_amdgcn_mfma_f32_16x16x32_bf16(ah[kb + 1].b, wfh[kb + 1][0], hB0, 0, 0, 0);
        hB1 = __builtin_amdgcn_mfma_f32_16x16x32_bf16(ah[kb + 1].b, wfh[kb + 1][1], hB1, 0, 0, 0);
        hC0 = __builtin_amdgcn_mfma_f32_16x16x32_bf16(ah[kb + 2].b, wfh[kb + 2][0], hC0, 0, 0, 0);
        hC1 = __builtin_amdgcn_mfma_f32_16x16x32_bf16(ah[kb + 2].b, wfh[kb + 2][1], hC1, 0, 0, 0);
        hD0 = __builtin_amdgcn_mfma_f32_16x16x32_bf16(ah[kb + 3].b, wfh[kb + 3][0], hD0, 0, 0, 0);
        hD1 = __builtin_amdgcn_mfma_f32_16x16x32_bf16(ah[kb + 3].b, wfh[kb + 3][1], hD1, 0, 0, 0);
      }
    }
    {
      f32x4 s0, s1, q0, q1;
#pragma unroll
      for (int r = 0; r < 4; ++r) {
        s0[r] = pxA0[r] + pxB0[r] + ((hA0[r] + hB0[r]) + (hC0[r] + hD0[r]));
        s1[r] = pxA1[r] + pxB1[r] + ((hA1[r] + hB1[r]) + (hC1[r] + hD1[r]));
      }
#pragma unroll
      for (int r = 0; r < 4; ++r) { q0[r] = __shfl_xor(s0[r], 8); q1[r] = __shfl_xor(s1[r], 8); }
      const bool lo = (lane & 8) == 0;
      float hv[4];
#pragma unroll
      for (int r = 0; r < 4; ++r) {
        float fr = lo ? s0[r] : q0[r];
        float ir = lo ? q0[r] : s0[r];
        float gr = lo ? s1[r] : q1[r];
        float orr = lo ? q1[r] : s1[r];
        float cc = sigf(fr + bF) * cst[r] + sigf(ir + bI) * tanhf_(gr + bG);
        cst[r] = cc;
        hv[r] = sigf(orr + bO) * tanhf_(cc);
      }
      if (lo) {
        int rbase = (wave << 4) + ((lane >> 4) << 2);
        u16* hp = Hl + (size_t)(t + 1) * slice + cg;
#pragma unroll
        for (int r = 0; r < 4; ++r)
          store_short_sc1(hp + (size_t)(rbase + r) * H_, (u32)f2bf(hv[r]));
      }
    }
    if (t + 1 < T_) do_x(t + 1);
  }
}

// ---------------- LayerNorm: Hbuf[2][t+1][b][:] -> Aln[b*T+t][:] bf16 ----------------
__global__ __launch_bounds__(64) void k_ln(const u16* __restrict__ H2,
                                           const float* __restrict__ gamma,
                                           const float* __restrict__ beta,
                                           u16* __restrict__ Aln) {
  int bt = blockIdx.x;
  int b = bt >> 7, t = bt & 127;
  const u16* src = H2 + ((size_t)(t + 1) * B_ + b) * H_;
  int l8 = threadIdx.x << 3;
  uint4 r = *(const uint4*)(src + l8);
  float v[8];
  v[0] = b2f(r.x & 0xffff); v[1] = b2f(r.x >> 16);
  v[2] = b2f(r.y & 0xffff); v[3] = b2f(r.y >> 16);
  v[4] = b2f(r.z & 0xffff); v[5] = b2f(r.z >> 16);
  v[6] = b2f(r.w & 0xffff); v[7] = b2f(r.w >> 16);
  float s = 0.f, sq = 0.f;
#pragma unroll
  for (int i = 0; i < 8; ++i) { s += v[i]; sq += v[i] * v[i]; }
#pragma unroll
  for (int off = 32; off > 0; off >>= 1) {
    s += __shfl_xor(s, off);
    sq += __shfl_xor(sq, off);
  }
  float mu = s * (1.f / 512.f);
  float inv = rsqrtf(sq * (1.f / 512.f) - mu * mu + 1e-5f);
  float4 g0 = *(const float4*)(gamma + l8), g1 = *(const float4*)(gamma + l8 + 4);
  float4 be0 = *(const float4*)(beta + l8), be1 = *(const float4*)(beta + l8 + 4);
  float gg[8] = {g0.x, g0.y, g0.z, g0.w, g1.x, g1.y, g1.z, g1.w};
  float bb[8] = {be0.x, be0.y, be0.z, be0.w, be1.x, be1.y, be1.z, be1.w};
  u16 o16[8];
#pragma unroll
  for (int i = 0; i < 8; ++i) o16[i] = f2bf((v[i] - mu) * inv * gg[i] + bb[i]);
  uint4 o;
  o.x = (u32)o16[0] | ((u32)o16[1] << 16);
  o.y = (u32)o16[2] | ((u32)o16[3] << 16);
  o.z = (u32)o16[4] | ((u32)o16[5] << 16);
  o.w = (u32)o16[6] | ((u32)o16[7] << 16);
  *(uint4*)(Aln + (size_t)bt * H_ + l8) = o;
}

// ---------------- projection: C[4096][32000] = Aln @ WhT^T + bh ----------------
// 256x256 tile, BK=32, 8 waves, triple-buffered swizzled LDS, counted vmcnt.
// Swizzle: byte ^= ((row>>1)&3)<<4 (conflict-free ds_read_b128 on 64B rows);
// applied on the global SOURCE for global_load_lds (linear dest) and on reads.
__global__ __launch_bounds__(512, 2) void k_gemm(const u16* __restrict__ A,
                                                 const u16* __restrict__ Bt,
                                                 const float* __restrict__ bh,
                                                 float* __restrict__ C) {
  __shared__ u16 As[3][256 * 32];
  __shared__ u16 Bs[3][256 * 32];
  const int tid = threadIdx.x, wave = tid >> 6, lane = tid & 63;
  const int mb = blockIdx.x / 125, nb = blockIdx.x % 125;
  const size_t arow0 = (size_t)mb << 8, bcol0 = (size_t)nb << 8;
  const int wm = wave >> 2, wn = wave & 3;  // 2 x 4 waves, each owns 128x64

  // staging geometry: thread covers LDS bytes tid*16 (rows 0..127) and
  // 8192+tid*16 (rows 128..255); source col pre-swizzled.
  const int srow = tid >> 2;                   // 0..127
  const int sq = (tid & 3) << 4;               // byte col in row
  const int sx = ((srow >> 1) & 3) << 4;       // swizzle xor (same for row+128)
  const int sqg = (sq ^ sx) >> 1;              // element col offset
  const u16* Arow0 = A + (arow0 + srow) * H_ + sqg;
  const u16* Arow1 = A + (arow0 + 128 + srow) * H_ + sqg;
  const u16* Brow0 = Bt + (bcol0 + srow) * H_ + sqg;
  const u16* Brow1 = Bt + (bcol0 + 128 + srow) * H_ + sqg;

  // fragment-read geometry: row = <frag>*16 + rA, kbyte = (kg*16) ^ xk
  const int rA = lane & 15, kg = lane >> 4;
  const int ko = (((kg << 4) ^ (((rA >> 1) & 3) << 4)) >> 1);  // u16 offset in row

  f32x4 acc[8][4];
  f32x4 z = {0.f, 0.f, 0.f, 0.f};
#pragma unroll
  for (int i = 0; i < 8; ++i)
#pragma unroll
    for (int j = 0; j < 4; ++j) acc[i][j] = z;

  auto stageA = [&](int kt, int c) {
    gload16(Arow0 + (kt << 5), &As[c][wave << 9]);
    gload16(Arow1 + (kt << 5), &As[c][4096 + (wave << 9)]);
  };
  auto stageB = [&](int kt, int c) {
    gload16(Brow0 + (kt << 5), &Bs[c][wave << 9]);
    gload16(Brow1 + (kt << 5), &Bs[c][4096 + (wave << 9)]);
  };

  // prologue: stage tiles 0 and 1
  stageA(0, 0); stageB(0, 0);
  stageA(1, 1); stageB(1, 1);
  asm volatile("s_waitcnt vmcnt(4)" ::: "memory");  // tile 0 landed
  __builtin_amdgcn_s_barrier();

  for (int kt = 0; kt < 16; ++kt) {
    const int c = kt % 3;
    const bool pre = (kt + 2 <= 15);
    const int c2 = (kt + 2) % 3;
    // ---- phase 0: B frags + A frags (mh=0); stage A(kt+2) ----
    bf16x8 bf[4], af[4];
#pragma unroll
    for (int ni = 0; ni < 4; ++ni)
      bf[ni] = *(const bf16x8*)&Bs[c][((wn << 6) + (ni << 4) + rA) * 32 + ko];
#pragma unroll
    for (int mi = 0; mi < 4; ++mi)
      af[mi] = *(const bf16x8*)&As[c][((wm << 7) + (mi << 4) + rA) * 32 + ko];
    if (pre) stageA(kt + 2, c2);
    __builtin_amdgcn_s_setprio(1);
#pragma unroll
    for (int mi = 0; mi < 4; ++mi)
#pragma unroll
      for (int ni = 0; ni < 4; ++ni)
        acc[mi][ni] = __builtin_amdgcn_mfma_f32_16x16x32_bf16(af[mi], bf[ni], acc[mi][ni], 0, 0, 0);
    __builtin_amdgcn_s_setprio(0);
    // ---- phase 1: A frags (mh=1); stage B(kt+2) ----
    bf16x8 af2[4];
#pragma unroll
    for (int mi = 0; mi < 4; ++mi)
      af2[mi] = *(const bf16x8*)&As[c][((wm << 7) + 64 + (mi << 4) + rA) * 32 + ko];
    if (pre) stageB(kt + 2, c2);
    __builtin_amdgcn_s_setprio(1);
#pragma unroll
    for (int mi = 0; mi < 4; ++mi)
#pragma unroll
      for (int ni = 0; ni < 4; ++ni)
        acc[4 + mi][ni] = __builtin_amdgcn_mfma_f32_16x16x32_bf16(af2[mi], bf[ni], acc[4 + mi][ni], 0, 0, 0);
    __builtin_amdgcn_s_setprio(0);
    // ---- boundary: tile kt+1 must be landed; never drain in-flight kt+2 ----
    if (kt < 15) {
      if (pre) {
        asm volatile("s_waitcnt vmcnt(4)" ::: "memory");
      } else {
        asm volatile("s_waitcnt vmcnt(0)" ::: "memory");
      }
      __builtin_amdgcn_sched_barrier(0);
      __builtin_amdgcn_s_barrier();
    }
  }

  // epilogue
  const int rb4 = (lane >> 4) << 2, n0 = lane & 15;
#pragma unroll
  for (int ni = 0; ni < 4; ++ni) {
    size_t col = bcol0 + (wn << 6) + (ni << 4) + n0;
    float bv = bh[col];
#pragma unroll
    for (int mi = 0; mi < 8; ++mi) {
      size_t row = arow0 + (wm << 7) + (mi << 4) + rb4;
#pragma unroll
      for (int r = 0; r < 4; ++r)
        C[(row + r) * V_ + col] = acc[mi][ni][r] + bv;
    }
  }
}

extern "C" void kernel_launch(void* const* d_in, const int* in_sizes, int n_in,
                              void* d_out, int out_size, void* d_ws, size_t ws_size,
                              hipStream_t stream) {
  const int* idx = (const int*)d_in[0];
  const float* emb = (const float*)d_in[1];
  const float* Wg = (const float*)d_in[2];
  const float* bias = (const float*)d_in[3];
  const float* gamma = (const float*)d_in[4];
  const float* beta = (const float*)d_in[5];
  const float* Wh = (const float*)d_in[6];
  const float* bh = (const float*)d_in[7];
  float* out = (float*)d_out;

  char* ws = (char*)d_ws;
  const size_t szX = (size_t)T_ * B_ * H_ * 2;             // x embedding, bf16
  const size_t szH = (size_t)L_ * (T_ + 1) * B_ * H_ * 2;  // h history, bf16
  const size_t szA = (size_t)B_ * T_ * H_ * 2;             // LN output, bf16
  const size_t szW = (size_t)V_ * H_ * 2;                  // WhT, bf16
  u16* X = (u16*)ws;
  u16* Hbuf = (u16*)(ws + szX);
  u16* Aln = (u16*)(ws + szX + szH);
  u16* WhT = (u16*)(ws + szX + szH + szA);
  if (ws_size < szX + szH + szA + szW) return;

  const size_t slice = (size_t)B_ * H_;
  // Sentinel fill (0xFF bytes -> bf16 0xFFFF, bit14=1) for all t>=1 slices;
  // slice 0 of each layer = h(-1) = 0.
  hipMemsetAsync(Hbuf, 0xFF, szH, stream);
  for (int l = 0; l < L_; ++l)
    hipMemsetAsync(Hbuf + (size_t)l * (T_ + 1) * slice, 0, slice * 2, stream);
  k_embed<<<B_ * T_, 64, 0, stream>>>(idx, emb, X);
  k_transpose<<<500 * 8, 256, 0, stream>>>(Wh, WhT);
  k_lstm<<<L_ * LW, 128, 0, stream>>>(Wg, bias, X, Hbuf);
  k_ln<<<B_ * T_, 64, 0, stream>>>(Hbuf + (size_t)2 * (T_ + 1) * B_ * H_, gamma, beta, Aln);
  k_gemm<<<16 * 125, 512, 0, stream>>>(Aln, WhT, bh, out);
}